// Round 6
// baseline (343.097 us; speedup 1.0000x reference)
//
#include <hip/hip_runtime.h>

// out[b,l] = bias[l] + sum_i x_i W1[i,l] + sum_ij x_i x_j W2[i,j,l]
//          + sum_ijk x_i x_j x_k W3[i,j,k,l];  B=32768, D=K=32, fp32 in/out.
//
// Feature-GEMM over unordered pairs (i<=j) of xt=[x,1] (33 symbols, 561 pairs),
// v_mfma_f32_32x32x16_f16, fp32 accumulate.
// R6 = R4 16-wave geometry (1024 thr, 8 pair-groups x 2 row-waves -> 4
// waves/SIMD; R5 at 2 waves/SIMD was latency-bound: MfmaUtil 22%, VALU 43%,
// occupancy 19%) with launch_bounds(1024,1) — no VGPR cap, so R4's
// 64-VGPR spill (840 MB scratch) cannot recur. Native _Float16 math (R5),
// depth-1 parity B-prefetch, MFMA interleaved acc0/acc1 for dep spacing.
// Algorithm floor: 1.147M MFMA x 32 SIMD-cyc / 1024 SIMD = ~15 us full-chip.

typedef _Float16 f16;
typedef __attribute__((ext_vector_type(2)))  _Float16 f16x2;
typedef __attribute__((ext_vector_type(4)))  _Float16 f16x4;
typedef __attribute__((ext_vector_type(8)))  _Float16 f16x8;
typedef __attribute__((ext_vector_type(16))) float    f32x16;

union AV { f16x2 h2[4];  f16x8 v;    };
union XR { f16x2 h2[16]; f16x8 v[4]; };

// group g (0..7) runs: pi = {g, 15-g, 16+g, 31-g, [32 iff g==0]}
// pair counts: g0=71, g1..g7=70.  Stream base = g ? 1+70g : 0.
__device__ __forceinline__ int run_pi(int g, int rr) {
    return rr == 0 ? g : rr == 1 ? 15 - g : rr == 2 ? 16 + g : rr == 3 ? 31 - g : 32;
}

// ---------------- prep: per-group sequential coefficient streams ----------------
// Slot (2048 B): [khalf(2)][col(32)][k16(16)] f16; slot order = group stream
// order (runs in rr order, j ascending).
__global__ void ntl_prep(const float* __restrict__ W1, const float* __restrict__ W2,
                         const float* __restrict__ W3, f16* __restrict__ Gimg) {
    int tid = blockIdx.x * 256 + threadIdx.x;
    if (tid >= 561 * 1024) return;
    int k    = tid & 31;
    int col  = (tid >> 5) & 31;
    int slot = tid >> 10;
    int g = 0;
    while (g < 7 && slot >= 1 + 70 * (g + 1)) ++g;
    int s = slot - (g ? 1 + 70 * g : 0);
    int rr = 0, pi, len;
    for (;;) { pi = run_pi(g, rr); len = 33 - pi; if (s < len) break; s -= len; ++rr; }
    int j = pi + s;             // pi <= j <= 32
    float v;
    if (j < 32) {
        v = W3[((pi * 32 + j) * 32 + k) * 32 + col];
        if (pi != j) v += W3[((j * 32 + pi) * 32 + k) * 32 + col];
    } else if (pi < 32) {
        v = W2[(pi * 32 + k) * 32 + col];
    } else {
        v = W1[k * 32 + col];
    }
    Gimg[slot * 1024 + (k >> 4) * 512 + col * 16 + (k & 15)] = (f16)v;
}

// ---------------- main kernel ----------------
// grid 256 x 1024 (16 waves = 4/SIMD). Block = 128 rows. Wave w: g=w>>1
// (8 pair groups), gw=w&1 -> rows gw*64..+63 (2 MFMA row tiles). Main loop:
// no LDS traffic, no barriers; B streamed from the L2-resident image.

#define XE(XR_, J) ((XR_).h2[(J) >> 1][(J) & 1])
#define MM(ACC, A, B) (ACC) = __builtin_amdgcn_mfma_f32_32x32x16_f16((A), (B), (ACC), 0, 0, 0)

#define PB(J)                                                                          \
    {                                                                                  \
        if ((J) < 32) { /* prefetch pair J+1 into opposite-parity regs */              \
            if (((J) & 1) == 0) { boa = *(const f16x8*)gp; bob = *(const f16x8*)(gp + 1024); } \
            else                { bea = *(const f16x8*)gp; beb = *(const f16x8*)(gp + 1024); } \
            gp += 2048;                                                                \
        }                                                                              \
        const f16x8 Ba = ((J) & 1) ? boa : bea;                                        \
        const f16x8 Bb = ((J) & 1) ? bob : beb;                                        \
        if ((J) == 32) { /* xt_j = 1: A-frag = yk directly */                          \
            MM(acc0, yk0[0].v, Ba); MM(acc1, yk1[0].v, Ba);                            \
            MM(acc0, yk0[1].v, Bb); MM(acc1, yk1[1].v, Bb);                            \
        } else {                                                                       \
            f16 t0 = XE(xa, (J)); f16x2 xj0 = {t0, t0};                                \
            f16 t1 = XE(xb, (J)); f16x2 xj1 = {t1, t1};                                \
            AV a0, a1;                                                                 \
            a0.h2[0] = xj0 * yk0[0].h2[0]; a0.h2[1] = xj0 * yk0[0].h2[1];              \
            a0.h2[2] = xj0 * yk0[0].h2[2]; a0.h2[3] = xj0 * yk0[0].h2[3];              \
            MM(acc0, a0.v, Ba);                                                        \
            a1.h2[0] = xj1 * yk1[0].h2[0]; a1.h2[1] = xj1 * yk1[0].h2[1];              \
            a1.h2[2] = xj1 * yk1[0].h2[2]; a1.h2[3] = xj1 * yk1[0].h2[3];              \
            MM(acc1, a1.v, Ba);                                                        \
            a0.h2[0] = xj0 * yk0[1].h2[0]; a0.h2[1] = xj0 * yk0[1].h2[1];              \
            a0.h2[2] = xj0 * yk0[1].h2[2]; a0.h2[3] = xj0 * yk0[1].h2[3];              \
            MM(acc0, a0.v, Bb);                                                        \
            a1.h2[0] = xj1 * yk1[1].h2[0]; a1.h2[1] = xj1 * yk1[1].h2[1];              \
            a1.h2[2] = xj1 * yk1[1].h2[2]; a1.h2[3] = xj1 * yk1[1].h2[3];              \
            MM(acc1, a1.v, Bb);                                                        \
        }                                                                              \
    }

__global__ __launch_bounds__(1024, 1) void ntl_main(const float* __restrict__ X,
                                                    const float* __restrict__ bias,
                                                    const f16* __restrict__ Gimg,
                                                    float* __restrict__ out) {
    __shared__ f16   xbuf[128 * 40];             // 10240 B, row stride 40 halves
    __shared__ float red[7 * 2 * 2 * 16 * 64];   // 114688 B cross-group reduce

    const int tid = (int)threadIdx.x;
    const int w   = tid >> 6;
    const int l   = tid & 63;
    const int g   = w >> 1;      // pair group 0..7
    const int gw  = w & 1;       // row-half
    const int h   = l >> 5;      // k-half
    const int lr  = l & 31;      // A row within tile / B col
    const long rowbase = (long)blockIdx.x * 128;

    // ---- prologue: x tile -> LDS (f16) ----
    {
        int r0 = tid >> 3, cb = (tid & 7) * 4;
        const float* xp = X + (rowbase + r0) * 32 + cb;
        float4 f0 = *(const float4*)xp;
        f16x4 o = {(f16)f0.x, (f16)f0.y, (f16)f0.z, (f16)f0.w};
        *(f16x4*)&xbuf[r0 * 40 + cb] = o;
        if ((tid & 7) == 0) xbuf[r0 * 40 + 32] = (f16)1.0f;
    }
    __syncthreads();

    XR xa, xb;   // this lane's two x rows (halves 0..31), in registers
    {
        const f16x8* p0 = (const f16x8*)&xbuf[(gw * 64 + lr) * 40];
        const f16x8* p1 = (const f16x8*)&xbuf[(gw * 64 + 32 + lr) * 40];
        xa.v[0] = p0[0]; xa.v[1] = p0[1]; xa.v[2] = p0[2]; xa.v[3] = p0[3];
        xb.v[0] = p1[0]; xb.v[1] = p1[1]; xb.v[2] = p1[2]; xb.v[3] = p1[3];
    }

    f32x16 acc0, acc1;
#pragma unroll
    for (int q = 0; q < 16; ++q) { acc0[q] = 0.f; acc1[q] = 0.f; }

    const char* gp = (const char*)Gimg + (size_t)(g ? 1 + 70 * g : 0) * 2048 + lr * 32 + h * 16;
    f16x8 bea{}, beb{}, boa{}, bob{};
    const int nr = (g == 0) ? 5 : 4;

    for (int rr = 0; rr < nr; ++rr) {
        const int pi = run_pi(g, rr);
        f16 xp0 = xbuf[(gw * 64 + lr) * 40 + pi];
        f16 xp1 = xbuf[(gw * 64 + 32 + lr) * 40 + pi];
        f16x2 hp0 = {xp0, xp0}, hp1 = {xp1, xp1};
        AV yk0[2], yk1[2];   // run-invariant x_pi * x[k-slice], MFMA A layout
#pragma unroll
        for (int kh = 0; kh < 2; ++kh)
#pragma unroll
            for (int q = 0; q < 4; ++q) {
                yk0[kh].h2[q] = hp0 * (h ? xa.h2[kh * 8 + 4 + q] : xa.h2[kh * 8 + q]);
                yk1[kh].h2[q] = hp1 * (h ? xb.h2[kh * 8 + 4 + q] : xb.h2[kh * 8 + q]);
            }
        // head loads for pair (pi,pi) into parity buffer pi&1
        if (pi & 1) { boa = *(const f16x8*)gp; bob = *(const f16x8*)(gp + 1024); }
        else        { bea = *(const f16x8*)gp; beb = *(const f16x8*)(gp + 1024); }
        gp += 2048;

        switch (pi) {
            case 0:  PB(0)
            case 1:  PB(1)
            case 2:  PB(2)
            case 3:  PB(3)
            case 4:  PB(4)
            case 5:  PB(5)
            case 6:  PB(6)
            case 7:  PB(7)
            case 8:  PB(8)
            case 9:  PB(9)
            case 10: PB(10)
            case 11: PB(11)
            case 12: PB(12)
            case 13: PB(13)
            case 14: PB(14)
            case 15: PB(15)
            case 16: PB(16)
            case 17: PB(17)
            case 18: PB(18)
            case 19: PB(19)
            case 20: PB(20)
            case 21: PB(21)
            case 22: PB(22)
            case 23: PB(23)
            case 24: PB(24)
            case 25: PB(25)
            case 26: PB(26)
            case 27: PB(27)
            case 28: PB(28)
            case 29: PB(29)
            case 30: PB(30)
            case 31: PB(31)
            case 32: PB(32)
        }
    }

    // ---- cross-group reduce: groups 1..7 dump, group 0 adds + bias + stores ----
    if (g >= 1) {
        int base = ((g - 1) * 4 + gw * 2) * 16 * 64;
#pragma unroll
        for (int r = 0; r < 16; ++r) red[base + r * 64 + l] = acc0[r];
#pragma unroll
        for (int r = 0; r < 16; ++r) red[base + (16 + r) * 64 + l] = acc1[r];
    }
    __syncthreads();
    if (g == 0) {
        float bcol = bias[lr];
#pragma unroll
        for (int r = 0; r < 16; ++r) {
            int rowoff = (r & 3) + 8 * (r >> 2) + 4 * h;   // D layout (verified R2-R5)
            {
                float v = acc0[r] + bcol;
#pragma unroll
                for (int sg = 0; sg < 7; ++sg)
                    v += red[((sg * 4 + gw * 2) * 16 + r) * 64 + l];
                out[(rowbase + gw * 64 + rowoff) * 32 + lr] = v;
            }
            {
                float v = acc1[r] + bcol;
#pragma unroll
                for (int sg = 0; sg < 7; ++sg)
                    v += red[((sg * 4 + gw * 2 + 1) * 16 + r) * 64 + l];
                out[(rowbase + gw * 64 + 32 + rowoff) * 32 + lr] = v;
            }
        }
    }
}

extern "C" void kernel_launch(void* const* d_in, const int* in_sizes, int n_in,
                              void* d_out, int out_size, void* d_ws, size_t ws_size,
                              hipStream_t stream) {
    const float* X    = (const float*)d_in[0];
    const float* W1   = (const float*)d_in[1];
    const float* W2   = (const float*)d_in[2];
    const float* W3   = (const float*)d_in[3];
    const float* bias = (const float*)d_in[4];
    float* out = (float*)d_out;
    f16* Gimg = (f16*)d_ws;   // 561 * 2048 B = 1.15 MB

    int prep_threads = 561 * 1024;
    ntl_prep<<<dim3((prep_threads + 255) / 256), dim3(256), 0, stream>>>(W1, W2, W3, Gimg);
    ntl_main<<<dim3(256), dim3(1024), 0, stream>>>(X, bias, Gimg, out);
}

// Round 7
// 339.316 us; speedup vs baseline: 1.0111x; 1.0111x over previous
//
#include <hip/hip_runtime.h>

// out[b,l] = bias[l] + sum_i x_i W1[i,l] + sum_ij x_i x_j W2[i,j,l]
//          + sum_ijk x_i x_j x_k W3[i,j,k,l];  B=32768, D=K=32, fp32 in/out.
//
// Feature-GEMM over unordered pairs (i<=j) of xt=[x,1] (33 symbols, 561 pairs),
// v_mfma_f32_32x32x16_f16, fp32 accumulate.
// R7: 4 waves/SIMD via 2 blocks/CU (grid 512 x 512thr, 64 rows/block,
// lb(512,4) -> VGPR cap 128), NOT via 1024-thr blocks: hipcc caps 1024-thr
// blocks at 64 VGPR regardless of lb second arg (R4: lb(1024,4)->64 VGPR,
// R6: lb(1024,1)->64 VGPR, both ~360MB scratch spill; R3/R5 512-thr ->
// 128 VGPR, no spill). 8 pair-groups x 1 wave each; per-wave inner state =
// R5's proven-fit loop minus the depth-2 rotation (~16 VGPR saved).
// Floors: MFMA 14.9 us; L2 stream 512 blk x 561 x 2KB = 588 MB ~ 17 us.

typedef _Float16 f16;
typedef __attribute__((ext_vector_type(2)))  _Float16 f16x2;
typedef __attribute__((ext_vector_type(4)))  _Float16 f16x4;
typedef __attribute__((ext_vector_type(8)))  _Float16 f16x8;
typedef __attribute__((ext_vector_type(16))) float    f32x16;

union AV { f16x2 h2[4];  f16x8 v;    };
union XR { f16x2 h2[16]; f16x8 v[4]; };

// group g (0..7) runs: pi = {g, 15-g, 16+g, 31-g, [32 iff g==0]}
// pair counts: g0=71, g1..g7=70.  Stream base = g ? 1+70g : 0.
__device__ __forceinline__ int run_pi(int g, int rr) {
    return rr == 0 ? g : rr == 1 ? 15 - g : rr == 2 ? 16 + g : rr == 3 ? 31 - g : 32;
}

// ---------------- prep: per-group sequential coefficient streams ----------------
// Slot (2048 B): [khalf(2)][col(32)][k16(16)] f16; slot order = group stream
// order (runs in rr order, j ascending).
__global__ void ntl_prep(const float* __restrict__ W1, const float* __restrict__ W2,
                         const float* __restrict__ W3, f16* __restrict__ Gimg) {
    int tid = blockIdx.x * 256 + threadIdx.x;
    if (tid >= 561 * 1024) return;
    int k    = tid & 31;
    int col  = (tid >> 5) & 31;
    int slot = tid >> 10;
    int g = 0;
    while (g < 7 && slot >= 1 + 70 * (g + 1)) ++g;
    int s = slot - (g ? 1 + 70 * g : 0);
    int rr = 0, pi, len;
    for (;;) { pi = run_pi(g, rr); len = 33 - pi; if (s < len) break; s -= len; ++rr; }
    int j = pi + s;             // pi <= j <= 32
    float v;
    if (j < 32) {
        v = W3[((pi * 32 + j) * 32 + k) * 32 + col];
        if (pi != j) v += W3[((j * 32 + pi) * 32 + k) * 32 + col];
    } else if (pi < 32) {
        v = W2[(pi * 32 + k) * 32 + col];
    } else {
        v = W1[k * 32 + col];
    }
    Gimg[slot * 1024 + (k >> 4) * 512 + col * 16 + (k & 15)] = (f16)v;
}

// ---------------- main kernel ----------------
// grid 512 x 512 (8 waves; 2 blocks/CU -> 4 waves/SIMD). Block = 64 rows
// (2 MFMA row tiles, both owned by every wave). Wave w = pair group 0..7.
// Main loop: no LDS traffic, no barriers; B streamed from L2-resident image.

#define XE(XR_, J) ((XR_).h2[(J) >> 1][(J) & 1])
#define MM(ACC, A, B) (ACC) = __builtin_amdgcn_mfma_f32_32x32x16_f16((A), (B), (ACC), 0, 0, 0)

#define PB(J)                                                                          \
    {                                                                                  \
        if ((J) < 32) { /* prefetch pair J+1 into opposite-parity regs */              \
            if (((J) & 1) == 0) { boa = *(const f16x8*)gp; bob = *(const f16x8*)(gp + 1024); } \
            else                { bea = *(const f16x8*)gp; beb = *(const f16x8*)(gp + 1024); } \
            gp += 2048;                                                                \
        }                                                                              \
        const f16x8 Ba = ((J) & 1) ? boa : bea;                                        \
        const f16x8 Bb = ((J) & 1) ? bob : beb;                                        \
        if ((J) == 32) { /* xt_j = 1: A-frag = yk directly */                          \
            MM(acc0, yk0[0].v, Ba); MM(acc1, yk1[0].v, Ba);                            \
            MM(acc0, yk0[1].v, Bb); MM(acc1, yk1[1].v, Bb);                            \
        } else {                                                                       \
            f16 t0 = XE(xa, (J)); f16x2 xj0 = {t0, t0};                                \
            f16 t1 = XE(xb, (J)); f16x2 xj1 = {t1, t1};                                \
            AV a0, a1;                                                                 \
            a0.h2[0] = xj0 * yk0[0].h2[0]; a0.h2[1] = xj0 * yk0[0].h2[1];              \
            a0.h2[2] = xj0 * yk0[0].h2[2]; a0.h2[3] = xj0 * yk0[0].h2[3];              \
            MM(acc0, a0.v, Ba);                                                        \
            a1.h2[0] = xj1 * yk1[0].h2[0]; a1.h2[1] = xj1 * yk1[0].h2[1];              \
            a1.h2[2] = xj1 * yk1[0].h2[2]; a1.h2[3] = xj1 * yk1[0].h2[3];              \
            MM(acc1, a1.v, Ba);                                                        \
            a0.h2[0] = xj0 * yk0[1].h2[0]; a0.h2[1] = xj0 * yk0[1].h2[1];              \
            a0.h2[2] = xj0 * yk0[1].h2[2]; a0.h2[3] = xj0 * yk0[1].h2[3];              \
            MM(acc0, a0.v, Bb);                                                        \
            a1.h2[0] = xj1 * yk1[1].h2[0]; a1.h2[1] = xj1 * yk1[1].h2[1];              \
            a1.h2[2] = xj1 * yk1[1].h2[2]; a1.h2[3] = xj1 * yk1[1].h2[3];              \
            MM(acc1, a1.v, Bb);                                                        \
        }                                                                              \
    }

__global__ __launch_bounds__(512, 4) void ntl_main(const float* __restrict__ X,
                                                   const float* __restrict__ bias,
                                                   const f16* __restrict__ Gimg,
                                                   float* __restrict__ out) {
    __shared__ f16   xbuf[64 * 40];          // 5120 B, row stride 40 halves
    __shared__ float red[7 * 2 * 16 * 64];   // 57344 B cross-group reduce

    const int tid = (int)threadIdx.x;
    const int w   = tid >> 6;    // pair group 0..7
    const int l   = tid & 63;
    const int h   = l >> 5;      // k-half
    const int lr  = l & 31;      // A row within tile / B col
    const long rowbase = (long)blockIdx.x * 64;

    // ---- prologue: x tile -> LDS (f16) ----
    {
        int r0 = tid >> 3, cb = (tid & 7) * 4;
        const float* xp = X + (rowbase + r0) * 32 + cb;
        float4 f0 = *(const float4*)xp;
        f16x4 o = {(f16)f0.x, (f16)f0.y, (f16)f0.z, (f16)f0.w};
        *(f16x4*)&xbuf[r0 * 40 + cb] = o;
        if ((tid & 7) == 0) xbuf[r0 * 40 + 32] = (f16)1.0f;
    }
    __syncthreads();

    XR xa, xb;   // this lane's two x rows (lr and 32+lr), in registers
    {
        const f16x8* p0 = (const f16x8*)&xbuf[lr * 40];
        const f16x8* p1 = (const f16x8*)&xbuf[(32 + lr) * 40];
        xa.v[0] = p0[0]; xa.v[1] = p0[1]; xa.v[2] = p0[2]; xa.v[3] = p0[3];
        xb.v[0] = p1[0]; xb.v[1] = p1[1]; xb.v[2] = p1[2]; xb.v[3] = p1[3];
    }

    f32x16 acc0, acc1;
#pragma unroll
    for (int q = 0; q < 16; ++q) { acc0[q] = 0.f; acc1[q] = 0.f; }

    const char* gp = (const char*)Gimg + (size_t)(w ? 1 + 70 * w : 0) * 2048 + lr * 32 + h * 16;
    f16x8 bea{}, beb{}, boa{}, bob{};
    const int nr = (w == 0) ? 5 : 4;

    for (int rr = 0; rr < nr; ++rr) {
        const int pi = run_pi(w, rr);
        f16 xp0 = xbuf[lr * 40 + pi];
        f16 xp1 = xbuf[(32 + lr) * 40 + pi];
        f16x2 hp0 = {xp0, xp0}, hp1 = {xp1, xp1};
        AV yk0[2], yk1[2];   // run-invariant x_pi * x[k-slice], MFMA A layout
#pragma unroll
        for (int kh = 0; kh < 2; ++kh)
#pragma unroll
            for (int q = 0; q < 4; ++q) {
                yk0[kh].h2[q] = hp0 * (h ? xa.h2[kh * 8 + 4 + q] : xa.h2[kh * 8 + q]);
                yk1[kh].h2[q] = hp1 * (h ? xb.h2[kh * 8 + 4 + q] : xb.h2[kh * 8 + q]);
            }
        // head loads for pair (pi,pi) into parity buffer pi&1
        if (pi & 1) { boa = *(const f16x8*)gp; bob = *(const f16x8*)(gp + 1024); }
        else        { bea = *(const f16x8*)gp; beb = *(const f16x8*)(gp + 1024); }
        gp += 2048;

        switch (pi) {
            case 0:  PB(0)
            case 1:  PB(1)
            case 2:  PB(2)
            case 3:  PB(3)
            case 4:  PB(4)
            case 5:  PB(5)
            case 6:  PB(6)
            case 7:  PB(7)
            case 8:  PB(8)
            case 9:  PB(9)
            case 10: PB(10)
            case 11: PB(11)
            case 12: PB(12)
            case 13: PB(13)
            case 14: PB(14)
            case 15: PB(15)
            case 16: PB(16)
            case 17: PB(17)
            case 18: PB(18)
            case 19: PB(19)
            case 20: PB(20)
            case 21: PB(21)
            case 22: PB(22)
            case 23: PB(23)
            case 24: PB(24)
            case 25: PB(25)
            case 26: PB(26)
            case 27: PB(27)
            case 28: PB(28)
            case 29: PB(29)
            case 30: PB(30)
            case 31: PB(31)
            case 32: PB(32)
        }
    }

    // ---- cross-group reduce: groups 1..7 dump, group 0 adds + bias + stores ----
    if (w >= 1) {
        int base = (w - 1) * 2 * 16 * 64;
#pragma unroll
        for (int r = 0; r < 16; ++r) red[base + r * 64 + l] = acc0[r];
#pragma unroll
        for (int r = 0; r < 16; ++r) red[base + (16 + r) * 64 + l] = acc1[r];
    }
    __syncthreads();
    if (w == 0) {
        float bcol = bias[lr];
#pragma unroll
        for (int r = 0; r < 16; ++r) {
            int rowoff = (r & 3) + 8 * (r >> 2) + 4 * h;   // D layout (verified R2-R6)
            {
                float v = acc0[r] + bcol;
#pragma unroll
                for (int sg = 0; sg < 7; ++sg)
                    v += red[(sg * 2 * 16 + r) * 64 + l];
                out[(rowbase + rowoff) * 32 + lr] = v;
            }
            {
                float v = acc1[r] + bcol;
#pragma unroll
                for (int sg = 0; sg < 7; ++sg)
                    v += red[((sg * 2 + 1) * 16 + r) * 64 + l];
                out[(rowbase + 32 + rowoff) * 32 + lr] = v;
            }
        }
    }
}

extern "C" void kernel_launch(void* const* d_in, const int* in_sizes, int n_in,
                              void* d_out, int out_size, void* d_ws, size_t ws_size,
                              hipStream_t stream) {
    const float* X    = (const float*)d_in[0];
    const float* W1   = (const float*)d_in[1];
    const float* W2   = (const float*)d_in[2];
    const float* W3   = (const float*)d_in[3];
    const float* bias = (const float*)d_in[4];
    float* out = (float*)d_out;
    f16* Gimg = (f16*)d_ws;   // 561 * 2048 B = 1.15 MB

    int prep_threads = 561 * 1024;
    ntl_prep<<<dim3((prep_threads + 255) / 256), dim3(256), 0, stream>>>(W1, W2, W3, Gimg);
    ntl_main<<<dim3(512), dim3(512), 0, stream>>>(X, bias, Gimg, out);
}

// Round 8
// 66.323 us; speedup vs baseline: 5.1731x; 5.1161x over previous
//
#include <hip/hip_runtime.h>

// out[b,l] = bias[l] + sum_i x_i W1[i,l] + sum_ij x_i x_j W2[i,j,l]
//          + sum_ijk x_i x_j x_k W3[i,j,k,l];  B=32768, D=K=32, fp32 in/out.
//
// Feature-GEMM over unordered pairs (i<=j) of xt=[x,1] (33 symbols, 561 pairs),
// v_mfma_f32_32x32x16_f16, fp32 accumulate.
// R8 = R7 geometry (grid 512 x 512thr, 64 rows/block, 2 blocks/CU -> 16
// waves/CU = 4 waves/SIMD by RESOURCES: 128 VGPR/wave allows 4 waves/SIMD,
// LDS 62.5KB allows 2 blocks/CU) with lb(512,2).
// LAUNCH_BOUNDS LESSON (R3-R7 matrix): hipcc's allocation cap follows
// arg2 like min-BLOCKS/CU: lb(512,2)->128 VGPR ok; lb(512,4)->64 VGPR,
// ~700MB scratch spill (R7); lb(1024,*)->64 VGPR (R4,R6). Use arg2=2 and
// let HW resources set occupancy.
// Floors: MFMA 15 us full-chip; L2 stream 512 blk x 1.15 MB = 588 MB ~17 us.

typedef _Float16 f16;
typedef __attribute__((ext_vector_type(2)))  _Float16 f16x2;
typedef __attribute__((ext_vector_type(4)))  _Float16 f16x4;
typedef __attribute__((ext_vector_type(8)))  _Float16 f16x8;
typedef __attribute__((ext_vector_type(16))) float    f32x16;

union AV { f16x2 h2[4];  f16x8 v;    };
union XR { f16x2 h2[16]; f16x8 v[4]; };

// group g (0..7) runs: pi = {g, 15-g, 16+g, 31-g, [32 iff g==0]}
// pair counts: g0=71, g1..g7=70.  Stream base = g ? 1+70g : 0.
__device__ __forceinline__ int run_pi(int g, int rr) {
    return rr == 0 ? g : rr == 1 ? 15 - g : rr == 2 ? 16 + g : rr == 3 ? 31 - g : 32;
}

// ---------------- prep: per-group sequential coefficient streams ----------------
// Slot (2048 B): [khalf(2)][col(32)][k16(16)] f16; slot order = group stream
// order (runs in rr order, j ascending).
__global__ void ntl_prep(const float* __restrict__ W1, const float* __restrict__ W2,
                         const float* __restrict__ W3, f16* __restrict__ Gimg) {
    int tid = blockIdx.x * 256 + threadIdx.x;
    if (tid >= 561 * 1024) return;
    int k    = tid & 31;
    int col  = (tid >> 5) & 31;
    int slot = tid >> 10;
    int g = 0;
    while (g < 7 && slot >= 1 + 70 * (g + 1)) ++g;
    int s = slot - (g ? 1 + 70 * g : 0);
    int rr = 0, pi, len;
    for (;;) { pi = run_pi(g, rr); len = 33 - pi; if (s < len) break; s -= len; ++rr; }
    int j = pi + s;             // pi <= j <= 32
    float v;
    if (j < 32) {
        v = W3[((pi * 32 + j) * 32 + k) * 32 + col];
        if (pi != j) v += W3[((j * 32 + pi) * 32 + k) * 32 + col];
    } else if (pi < 32) {
        v = W2[(pi * 32 + k) * 32 + col];
    } else {
        v = W1[k * 32 + col];
    }
    Gimg[slot * 1024 + (k >> 4) * 512 + col * 16 + (k & 15)] = (f16)v;
}

// ---------------- main kernel ----------------
// grid 512 x 512 (8 waves; 2 blocks/CU -> 4 waves/SIMD). Block = 64 rows
// (2 MFMA row tiles, both owned by every wave). Wave w = pair group 0..7.
// Main loop: no LDS traffic, no barriers; B streamed from L2-resident image.

#define XE(XR_, J) ((XR_).h2[(J) >> 1][(J) & 1])
#define MM(ACC, A, B) (ACC) = __builtin_amdgcn_mfma_f32_32x32x16_f16((A), (B), (ACC), 0, 0, 0)

#define PB(J)                                                                          \
    {                                                                                  \
        if ((J) < 32) { /* prefetch pair J+1 into opposite-parity regs */              \
            if (((J) & 1) == 0) { boa = *(const f16x8*)gp; bob = *(const f16x8*)(gp + 1024); } \
            else                { bea = *(const f16x8*)gp; beb = *(const f16x8*)(gp + 1024); } \
            gp += 2048;                                                                \
        }                                                                              \
        const f16x8 Ba = ((J) & 1) ? boa : bea;                                        \
        const f16x8 Bb = ((J) & 1) ? bob : beb;                                        \
        if ((J) == 32) { /* xt_j = 1: A-frag = yk directly */                          \
            MM(acc0, yk0[0].v, Ba); MM(acc1, yk1[0].v, Ba);                            \
            MM(acc0, yk0[1].v, Bb); MM(acc1, yk1[1].v, Bb);                            \
        } else {                                                                       \
            f16 t0 = XE(xa, (J)); f16x2 xj0 = {t0, t0};                                \
            f16 t1 = XE(xb, (J)); f16x2 xj1 = {t1, t1};                                \
            AV a0, a1;                                                                 \
            a0.h2[0] = xj0 * yk0[0].h2[0]; a0.h2[1] = xj0 * yk0[0].h2[1];              \
            a0.h2[2] = xj0 * yk0[0].h2[2]; a0.h2[3] = xj0 * yk0[0].h2[3];              \
            MM(acc0, a0.v, Ba);                                                        \
            a1.h2[0] = xj1 * yk1[0].h2[0]; a1.h2[1] = xj1 * yk1[0].h2[1];              \
            a1.h2[2] = xj1 * yk1[0].h2[2]; a1.h2[3] = xj1 * yk1[0].h2[3];              \
            MM(acc1, a1.v, Ba);                                                        \
            a0.h2[0] = xj0 * yk0[1].h2[0]; a0.h2[1] = xj0 * yk0[1].h2[1];              \
            a0.h2[2] = xj0 * yk0[1].h2[2]; a0.h2[3] = xj0 * yk0[1].h2[3];              \
            MM(acc0, a0.v, Bb);                                                        \
            a1.h2[0] = xj1 * yk1[1].h2[0]; a1.h2[1] = xj1 * yk1[1].h2[1];              \
            a1.h2[2] = xj1 * yk1[1].h2[2]; a1.h2[3] = xj1 * yk1[1].h2[3];              \
            MM(acc1, a1.v, Bb);                                                        \
        }                                                                              \
    }

__global__ __launch_bounds__(512, 2) void ntl_main(const float* __restrict__ X,
                                                   const float* __restrict__ bias,
                                                   const f16* __restrict__ Gimg,
                                                   float* __restrict__ out) {
    __shared__ f16   xbuf[64 * 40];          // 5120 B, row stride 40 halves
    __shared__ float red[7 * 2 * 16 * 64];   // 57344 B cross-group reduce

    const int tid = (int)threadIdx.x;
    const int w   = tid >> 6;    // pair group 0..7
    const int l   = tid & 63;
    const int h   = l >> 5;      // k-half
    const int lr  = l & 31;      // A row within tile / B col
    const long rowbase = (long)blockIdx.x * 64;

    // ---- prologue: x tile -> LDS (f16) ----
    {
        int r0 = tid >> 3, cb = (tid & 7) * 4;
        const float* xp = X + (rowbase + r0) * 32 + cb;
        float4 f0 = *(const float4*)xp;
        f16x4 o = {(f16)f0.x, (f16)f0.y, (f16)f0.z, (f16)f0.w};
        *(f16x4*)&xbuf[r0 * 40 + cb] = o;
        if ((tid & 7) == 0) xbuf[r0 * 40 + 32] = (f16)1.0f;
    }
    __syncthreads();

    XR xa, xb;   // this lane's two x rows (lr and 32+lr), in registers
    {
        const f16x8* p0 = (const f16x8*)&xbuf[lr * 40];
        const f16x8* p1 = (const f16x8*)&xbuf[(32 + lr) * 40];
        xa.v[0] = p0[0]; xa.v[1] = p0[1]; xa.v[2] = p0[2]; xa.v[3] = p0[3];
        xb.v[0] = p1[0]; xb.v[1] = p1[1]; xb.v[2] = p1[2]; xb.v[3] = p1[3];
    }

    f32x16 acc0, acc1;
#pragma unroll
    for (int q = 0; q < 16; ++q) { acc0[q] = 0.f; acc1[q] = 0.f; }

    const char* gp = (const char*)Gimg + (size_t)(w ? 1 + 70 * w : 0) * 2048 + lr * 32 + h * 16;
    f16x8 bea{}, beb{}, boa{}, bob{};
    const int nr = (w == 0) ? 5 : 4;

    for (int rr = 0; rr < nr; ++rr) {
        const int pi = run_pi(w, rr);
        f16 xp0 = xbuf[lr * 40 + pi];
        f16 xp1 = xbuf[(32 + lr) * 40 + pi];
        f16x2 hp0 = {xp0, xp0}, hp1 = {xp1, xp1};
        AV yk0[2], yk1[2];   // run-invariant x_pi * x[k-slice], MFMA A layout
#pragma unroll
        for (int kh = 0; kh < 2; ++kh)
#pragma unroll
            for (int q = 0; q < 4; ++q) {
                yk0[kh].h2[q] = hp0 * (h ? xa.h2[kh * 8 + 4 + q] : xa.h2[kh * 8 + q]);
                yk1[kh].h2[q] = hp1 * (h ? xb.h2[kh * 8 + 4 + q] : xb.h2[kh * 8 + q]);
            }
        // head loads for pair (pi,pi) into parity buffer pi&1
        if (pi & 1) { boa = *(const f16x8*)gp; bob = *(const f16x8*)(gp + 1024); }
        else        { bea = *(const f16x8*)gp; beb = *(const f16x8*)(gp + 1024); }
        gp += 2048;

        switch (pi) {
            case 0:  PB(0)
            case 1:  PB(1)
            case 2:  PB(2)
            case 3:  PB(3)
            case 4:  PB(4)
            case 5:  PB(5)
            case 6:  PB(6)
            case 7:  PB(7)
            case 8:  PB(8)
            case 9:  PB(9)
            case 10: PB(10)
            case 11: PB(11)
            case 12: PB(12)
            case 13: PB(13)
            case 14: PB(14)
            case 15: PB(15)
            case 16: PB(16)
            case 17: PB(17)
            case 18: PB(18)
            case 19: PB(19)
            case 20: PB(20)
            case 21: PB(21)
            case 22: PB(22)
            case 23: PB(23)
            case 24: PB(24)
            case 25: PB(25)
            case 26: PB(26)
            case 27: PB(27)
            case 28: PB(28)
            case 29: PB(29)
            case 30: PB(30)
            case 31: PB(31)
            case 32: PB(32)
        }
    }

    // ---- cross-group reduce: groups 1..7 dump, group 0 adds + bias + stores ----
    if (w >= 1) {
        int base = (w - 1) * 2 * 16 * 64;
#pragma unroll
        for (int r = 0; r < 16; ++r) red[base + r * 64 + l] = acc0[r];
#pragma unroll
        for (int r = 0; r < 16; ++r) red[base + (16 + r) * 64 + l] = acc1[r];
    }
    __syncthreads();
    if (w == 0) {
        float bcol = bias[lr];
#pragma unroll
        for (int r = 0; r < 16; ++r) {
            int rowoff = (r & 3) + 8 * (r >> 2) + 4 * h;   // D layout (verified R2-R7)
            {
                float v = acc0[r] + bcol;
#pragma unroll
                for (int sg = 0; sg < 7; ++sg)
                    v += red[(sg * 2 * 16 + r) * 64 + l];
                out[(rowbase + rowoff) * 32 + lr] = v;
            }
            {
                float v = acc1[r] + bcol;
#pragma unroll
                for (int sg = 0; sg < 7; ++sg)
                    v += red[((sg * 2 + 1) * 16 + r) * 64 + l];
                out[(rowbase + 32 + rowoff) * 32 + lr] = v;
            }
        }
    }
}

extern "C" void kernel_launch(void* const* d_in, const int* in_sizes, int n_in,
                              void* d_out, int out_size, void* d_ws, size_t ws_size,
                              hipStream_t stream) {
    const float* X    = (const float*)d_in[0];
    const float* W1   = (const float*)d_in[1];
    const float* W2   = (const float*)d_in[2];
    const float* W3   = (const float*)d_in[3];
    const float* bias = (const float*)d_in[4];
    float* out = (float*)d_out;
    f16* Gimg = (f16*)d_ws;   // 561 * 2048 B = 1.15 MB

    int prep_threads = 561 * 1024;
    ntl_prep<<<dim3((prep_threads + 255) / 256), dim3(256), 0, stream>>>(W1, W2, W3, Gimg);
    ntl_main<<<dim3(512), dim3(512), 0, stream>>>(X, bias, Gimg, out);
}

// Round 9
// 66.253 us; speedup vs baseline: 5.1786x; 1.0011x over previous
//
#include <hip/hip_runtime.h>

// out[b,l] = bias[l] + sum_i x_i W1[i,l] + sum_ij x_i x_j W2[i,j,l]
//          + sum_ijk x_i x_j x_k W3[i,j,k,l];  B=32768, D=K=32, fp32 in/out.
//
// Feature-GEMM over unordered pairs (i<=j) of xt=[x,1] (33 symbols, 561 pairs),
// v_mfma_f32_32x32x16_f16, fp32 accumulate.
// R9 = R8 (grid 512 x 512thr, 64 rows/block, lb(512,2) -> 128 VGPR no spill)
// with LDS cut 62.4KB -> 37.9KB via staged epilogue reduction (32KB buffer,
// two dump/add stages). R8 showed occupancy stuck at ~19% (8 waves/CU) even
// with 2 blocks/CU worth of grid: testing whether LDS was the binder.
// Floors: MFMA 15 us full-chip; L2 stream 588 MB ~17 us; VALU ~16 us.

typedef _Float16 f16;
typedef __attribute__((ext_vector_type(2)))  _Float16 f16x2;
typedef __attribute__((ext_vector_type(4)))  _Float16 f16x4;
typedef __attribute__((ext_vector_type(8)))  _Float16 f16x8;
typedef __attribute__((ext_vector_type(16))) float    f32x16;

union AV { f16x2 h2[4];  f16x8 v;    };
union XR { f16x2 h2[16]; f16x8 v[4]; };

// group g (0..7) runs: pi = {g, 15-g, 16+g, 31-g, [32 iff g==0]}
// pair counts: g0=71, g1..g7=70.  Stream base = g ? 1+70g : 0.
__device__ __forceinline__ int run_pi(int g, int rr) {
    return rr == 0 ? g : rr == 1 ? 15 - g : rr == 2 ? 16 + g : rr == 3 ? 31 - g : 32;
}

// ---------------- prep: per-group sequential coefficient streams ----------------
// Slot (2048 B): [khalf(2)][col(32)][k16(16)] f16; slot order = group stream
// order (runs in rr order, j ascending).
__global__ void ntl_prep(const float* __restrict__ W1, const float* __restrict__ W2,
                         const float* __restrict__ W3, f16* __restrict__ Gimg) {
    int tid = blockIdx.x * 256 + threadIdx.x;
    if (tid >= 561 * 1024) return;
    int k    = tid & 31;
    int col  = (tid >> 5) & 31;
    int slot = tid >> 10;
    int g = 0;
    while (g < 7 && slot >= 1 + 70 * (g + 1)) ++g;
    int s = slot - (g ? 1 + 70 * g : 0);
    int rr = 0, pi, len;
    for (;;) { pi = run_pi(g, rr); len = 33 - pi; if (s < len) break; s -= len; ++rr; }
    int j = pi + s;             // pi <= j <= 32
    float v;
    if (j < 32) {
        v = W3[((pi * 32 + j) * 32 + k) * 32 + col];
        if (pi != j) v += W3[((j * 32 + pi) * 32 + k) * 32 + col];
    } else if (pi < 32) {
        v = W2[(pi * 32 + k) * 32 + col];
    } else {
        v = W1[k * 32 + col];
    }
    Gimg[slot * 1024 + (k >> 4) * 512 + col * 16 + (k & 15)] = (f16)v;
}

// ---------------- main kernel ----------------
// grid 512 x 512 (8 waves). Block = 64 rows (2 MFMA row tiles, both owned by
// every wave). Wave w = pair group 0..7. Main loop: no LDS traffic, no
// barriers; B streamed from L2-resident image.

#define XE(XR_, J) ((XR_).h2[(J) >> 1][(J) & 1])
#define MM(ACC, A, B) (ACC) = __builtin_amdgcn_mfma_f32_32x32x16_f16((A), (B), (ACC), 0, 0, 0)

#define PB(J)                                                                          \
    {                                                                                  \
        if ((J) < 32) { /* prefetch pair J+1 into opposite-parity regs */              \
            if (((J) & 1) == 0) { boa = *(const f16x8*)gp; bob = *(const f16x8*)(gp + 1024); } \
            else                { bea = *(const f16x8*)gp; beb = *(const f16x8*)(gp + 1024); } \
            gp += 2048;                                                                \
        }                                                                              \
        const f16x8 Ba = ((J) & 1) ? boa : bea;                                        \
        const f16x8 Bb = ((J) & 1) ? bob : beb;                                        \
        if ((J) == 32) { /* xt_j = 1: A-frag = yk directly */                          \
            MM(acc0, yk0[0].v, Ba); MM(acc1, yk1[0].v, Ba);                            \
            MM(acc0, yk0[1].v, Bb); MM(acc1, yk1[1].v, Bb);                            \
        } else {                                                                       \
            f16 t0 = XE(xa, (J)); f16x2 xj0 = {t0, t0};                                \
            f16 t1 = XE(xb, (J)); f16x2 xj1 = {t1, t1};                                \
            AV a0, a1;                                                                 \
            a0.h2[0] = xj0 * yk0[0].h2[0]; a0.h2[1] = xj0 * yk0[0].h2[1];              \
            a0.h2[2] = xj0 * yk0[0].h2[2]; a0.h2[3] = xj0 * yk0[0].h2[3];              \
            MM(acc0, a0.v, Ba);                                                        \
            a1.h2[0] = xj1 * yk1[0].h2[0]; a1.h2[1] = xj1 * yk1[0].h2[1];              \
            a1.h2[2] = xj1 * yk1[0].h2[2]; a1.h2[3] = xj1 * yk1[0].h2[3];              \
            MM(acc1, a1.v, Ba);                                                        \
            a0.h2[0] = xj0 * yk0[1].h2[0]; a0.h2[1] = xj0 * yk0[1].h2[1];              \
            a0.h2[2] = xj0 * yk0[1].h2[2]; a0.h2[3] = xj0 * yk0[1].h2[3];              \
            MM(acc0, a0.v, Bb);                                                        \
            a1.h2[0] = xj1 * yk1[1].h2[0]; a1.h2[1] = xj1 * yk1[1].h2[1];              \
            a1.h2[2] = xj1 * yk1[1].h2[2]; a1.h2[3] = xj1 * yk1[1].h2[3];              \
            MM(acc1, a1.v, Bb);                                                        \
        }                                                                              \
    }

__global__ __launch_bounds__(512, 2) void ntl_main(const float* __restrict__ X,
                                                   const float* __restrict__ bias,
                                                   const f16* __restrict__ Gimg,
                                                   float* __restrict__ out) {
    __shared__ f16   xbuf[64 * 40];   // 5120 B, row stride 40 halves
    __shared__ float red[8192];       // 32768 B staged reduction buffer

    const int tid = (int)threadIdx.x;
    const int w   = tid >> 6;    // pair group 0..7
    const int l   = tid & 63;
    const int h   = l >> 5;      // k-half
    const int lr  = l & 31;      // A row within tile / B col
    const long rowbase = (long)blockIdx.x * 64;

    // ---- prologue: x tile -> LDS (f16) ----
    {
        int r0 = tid >> 3, cb = (tid & 7) * 4;
        const float* xp = X + (rowbase + r0) * 32 + cb;
        float4 f0 = *(const float4*)xp;
        f16x4 o = {(f16)f0.x, (f16)f0.y, (f16)f0.z, (f16)f0.w};
        *(f16x4*)&xbuf[r0 * 40 + cb] = o;
        if ((tid & 7) == 0) xbuf[r0 * 40 + 32] = (f16)1.0f;
    }
    __syncthreads();

    XR xa, xb;   // this lane's two x rows (lr and 32+lr), in registers
    {
        const f16x8* p0 = (const f16x8*)&xbuf[lr * 40];
        const f16x8* p1 = (const f16x8*)&xbuf[(32 + lr) * 40];
        xa.v[0] = p0[0]; xa.v[1] = p0[1]; xa.v[2] = p0[2]; xa.v[3] = p0[3];
        xb.v[0] = p1[0]; xb.v[1] = p1[1]; xb.v[2] = p1[2]; xb.v[3] = p1[3];
    }

    f32x16 acc0, acc1;
#pragma unroll
    for (int q = 0; q < 16; ++q) { acc0[q] = 0.f; acc1[q] = 0.f; }

    const char* gp = (const char*)Gimg + (size_t)(w ? 1 + 70 * w : 0) * 2048 + lr * 32 + h * 16;
    f16x8 bea{}, beb{}, boa{}, bob{};
    const int nr = (w == 0) ? 5 : 4;

    for (int rr = 0; rr < nr; ++rr) {
        const int pi = run_pi(w, rr);
        f16 xp0 = xbuf[lr * 40 + pi];
        f16 xp1 = xbuf[(32 + lr) * 40 + pi];
        f16x2 hp0 = {xp0, xp0}, hp1 = {xp1, xp1};
        AV yk0[2], yk1[2];   // run-invariant x_pi * x[k-slice], MFMA A layout
#pragma unroll
        for (int kh = 0; kh < 2; ++kh)
#pragma unroll
            for (int q = 0; q < 4; ++q) {
                yk0[kh].h2[q] = hp0 * (h ? xa.h2[kh * 8 + 4 + q] : xa.h2[kh * 8 + q]);
                yk1[kh].h2[q] = hp1 * (h ? xb.h2[kh * 8 + 4 + q] : xb.h2[kh * 8 + q]);
            }
        // head loads for pair (pi,pi) into parity buffer pi&1
        if (pi & 1) { boa = *(const f16x8*)gp; bob = *(const f16x8*)(gp + 1024); }
        else        { bea = *(const f16x8*)gp; beb = *(const f16x8*)(gp + 1024); }
        gp += 2048;

        switch (pi) {
            case 0:  PB(0)
            case 1:  PB(1)
            case 2:  PB(2)
            case 3:  PB(3)
            case 4:  PB(4)
            case 5:  PB(5)
            case 6:  PB(6)
            case 7:  PB(7)
            case 8:  PB(8)
            case 9:  PB(9)
            case 10: PB(10)
            case 11: PB(11)
            case 12: PB(12)
            case 13: PB(13)
            case 14: PB(14)
            case 15: PB(15)
            case 16: PB(16)
            case 17: PB(17)
            case 18: PB(18)
            case 19: PB(19)
            case 20: PB(20)
            case 21: PB(21)
            case 22: PB(22)
            case 23: PB(23)
            case 24: PB(24)
            case 25: PB(25)
            case 26: PB(26)
            case 27: PB(27)
            case 28: PB(28)
            case 29: PB(29)
            case 30: PB(30)
            case 31: PB(31)
            case 32: PB(32)
        }
    }

    // ---- staged cross-group reduce (32 KB buffer) ----
    // stage 1: waves 4-7 dump; waves 0-3 add partner (w+4)
    if (w >= 4) {
        int base = (w - 4) * 2048;
#pragma unroll
        for (int r = 0; r < 16; ++r) red[base + r * 64 + l] = acc0[r];
#pragma unroll
        for (int r = 0; r < 16; ++r) red[base + (16 + r) * 64 + l] = acc1[r];
    }
    __syncthreads();
    if (w < 4) {
        int base = w * 2048;
#pragma unroll
        for (int r = 0; r < 16; ++r) acc0[r] += red[base + r * 64 + l];
#pragma unroll
        for (int r = 0; r < 16; ++r) acc1[r] += red[base + (16 + r) * 64 + l];
    }
    __syncthreads();
    // stage 2: waves 1-3 dump; wave 0 adds all + bias + stores
    if (w >= 1 && w < 4) {
        int base = (w - 1) * 2048;
#pragma unroll
        for (int r = 0; r < 16; ++r) red[base + r * 64 + l] = acc0[r];
#pragma unroll
        for (int r = 0; r < 16; ++r) red[base + (16 + r) * 64 + l] = acc1[r];
    }
    __syncthreads();
    if (w == 0) {
        float bcol = bias[lr];
#pragma unroll
        for (int r = 0; r < 16; ++r) {
            int rowoff = (r & 3) + 8 * (r >> 2) + 4 * h;   // D layout (verified R2-R8)
            {
                float v = acc0[r] + bcol;
#pragma unroll
                for (int sg = 0; sg < 3; ++sg) v += red[sg * 2048 + r * 64 + l];
                out[(rowbase + rowoff) * 32 + lr] = v;
            }
            {
                float v = acc1[r] + bcol;
#pragma unroll
                for (int sg = 0; sg < 3; ++sg) v += red[sg * 2048 + (16 + r) * 64 + l];
                out[(rowbase + 32 + rowoff) * 32 + lr] = v;
            }
        }
    }
}

extern "C" void kernel_launch(void* const* d_in, const int* in_sizes, int n_in,
                              void* d_out, int out_size, void* d_ws, size_t ws_size,
                              hipStream_t stream) {
    const float* X    = (const float*)d_in[0];
    const float* W1   = (const float*)d_in[1];
    const float* W2   = (const float*)d_in[2];
    const float* W3   = (const float*)d_in[3];
    const float* bias = (const float*)d_in[4];
    float* out = (float*)d_out;
    f16* Gimg = (f16*)d_ws;   // 561 * 2048 B = 1.15 MB

    int prep_threads = 561 * 1024;
    ntl_prep<<<dim3((prep_threads + 255) / 256), dim3(256), 0, stream>>>(W1, W2, W3, Gimg);
    ntl_main<<<dim3(512), dim3(512), 0, stream>>>(X, bias, Gimg, out);
}